// Round 4
// baseline (301.076 us; speedup 1.0000x reference)
//
#include <hip/hip_runtime.h>

#define T_LEN  16384
#define SUB    16              // elements per sub-chunk (4 x float4)
#define NTHR   512             // threads per block; one row per block
#define NWAVE  (NTHR / 64)     // 8 waves
#define HALF   (T_LEN / 2)     // 8192

// Causal unbiased-EMA instance norm. One 512-thread block per (b,c) row.
// Thread owns TWO 16-elem sub-chunks: A at t=16*tid, B at t=8192+16*tid.
// 64B lane stride -> fully coalesced (proven clean in R3).
// Scan: local -> wave Hillis-Steele (decay a^(16*2^k)) -> 8+8 wave totals in
// LDS, one barrier -> carries for A and B -> recompute + fused normalize:
//   out = (x*w - s1) * rsqrt(s2*w - s1^2 + eps*w^2)    (no v_rcp per element)

__device__ __forceinline__ void process16(const float4* __restrict__ xv,
                                          float4* __restrict__ yv,
                                          float s1, float s2, float w) {
    const float A    = 0.99f;
    const float OMA  = (float)(1.0 - 0.99);
    const float EPSF = 1e-5f;
#pragma unroll
    for (int i = 0; i < 4; ++i) {
        float4 xq = xv[i];
        float4 oq;
#pragma unroll
        for (int e = 0; e < 4; ++e) {
            float xi = (e == 0) ? xq.x : (e == 1) ? xq.y : (e == 2) ? xq.z : xq.w;
            float t = OMA * xi;
            s1 = fmaf(A, s1, t);
            s2 = fmaf(A, s2, t * xi);
            w  = fmaf(A, w, OMA);
            float w2    = w * w;
            float numer = fmaf(xi, w, -s1);
            float arg   = fmaf(s2, w, fmaf(-s1, s1, EPSF * w2));
            float rs    = __builtin_amdgcn_rsqf(arg);
            float o     = numer * rs;
            if (e == 0) oq.x = o; else if (e == 1) oq.y = o; else if (e == 2) oq.z = o; else oq.w = o;
        }
        yv[i] = oq;
    }
}

__global__ __launch_bounds__(NTHR, 6)
void ema_norm_kernel(const float* __restrict__ x, float* __restrict__ y) {
    const float A   = 0.99f;
    const float OMA = (float)(1.0 - 0.99);
    const float Kf  = (float)((double)((float)(1.0 - 0.99)) / (1.0 - (double)0.99f));

    const int row  = blockIdx.x;
    const int tid  = threadIdx.x;
    const int lane = tid & 63;
    const int wid  = tid >> 6;

    const float* __restrict__ rowx = x + (size_t)row * T_LEN;
    float*       __restrict__ rowy = y + (size_t)row * T_LEN;

    const float4* __restrict__ xrA = reinterpret_cast<const float4*>(rowx + tid * SUB);
    const float4* __restrict__ xrB = reinterpret_cast<const float4*>(rowx + HALF + tid * SUB);
    float4* __restrict__ yrA = reinterpret_cast<float4*>(rowy + tid * SUB);
    float4* __restrict__ yrB = reinterpret_cast<float4*>(rowy + HALF + tid * SUB);

    // ---- load both sub-chunks (8 x float4) ----
    float4 xvA[4], xvB[4];
#pragma unroll
    for (int i = 0; i < 4; ++i) xvA[i] = xrA[i];
#pragma unroll
    for (int i = 0; i < 4; ++i) xvB[i] = xrB[i];

    // ---- local EMA scans from zero carry ----
    float sA1 = 0.f, sA2 = 0.f, sB1 = 0.f, sB2 = 0.f;
#pragma unroll
    for (int i = 0; i < 4; ++i) {
        float t;
        t = OMA * xvA[i].x; sA1 = fmaf(A, sA1, t); sA2 = fmaf(A, sA2, t * xvA[i].x);
        t = OMA * xvA[i].y; sA1 = fmaf(A, sA1, t); sA2 = fmaf(A, sA2, t * xvA[i].y);
        t = OMA * xvA[i].z; sA1 = fmaf(A, sA1, t); sA2 = fmaf(A, sA2, t * xvA[i].z);
        t = OMA * xvA[i].w; sA1 = fmaf(A, sA1, t); sA2 = fmaf(A, sA2, t * xvA[i].w);
        t = OMA * xvB[i].x; sB1 = fmaf(A, sB1, t); sB2 = fmaf(A, sB2, t * xvB[i].x);
        t = OMA * xvB[i].y; sB1 = fmaf(A, sB1, t); sB2 = fmaf(A, sB2, t * xvB[i].y);
        t = OMA * xvB[i].z; sB1 = fmaf(A, sB1, t); sB2 = fmaf(A, sB2, t * xvB[i].z);
        t = OMA * xvB[i].w; sB1 = fmaf(A, sB1, t); sB2 = fmaf(A, sB2, t * xvB[i].w);
    }

    // decay constants d[k] = alpha^(16 * 2^k), exact repeated squaring
    float a16 = A;
#pragma unroll
    for (int i = 0; i < 4; ++i) a16 *= a16;       // alpha^16
    float d[10];
    d[0] = a16;
#pragma unroll
    for (int k = 1; k < 10; ++k) d[k] = d[k - 1] * d[k - 1];

    // ---- wave-level inclusive scans (Hillis-Steele with decay), A and B ----
    float vA1 = sA1, vA2 = sA2, vB1 = sB1, vB2 = sB2;
#pragma unroll
    for (int k = 0; k < 6; ++k) {
        const int off = 1 << k;
        float oA1 = __shfl_up(vA1, off, 64);
        float oA2 = __shfl_up(vA2, off, 64);
        float oB1 = __shfl_up(vB1, off, 64);
        float oB2 = __shfl_up(vB2, off, 64);
        if (lane >= off) {
            vA1 = fmaf(d[k], oA1, vA1); vA2 = fmaf(d[k], oA2, vA2);
            vB1 = fmaf(d[k], oB1, vB1); vB2 = fmaf(d[k], oB2, vB2);
        }
    }
    // exclusive carries within wave
    float cA1 = __shfl_up(vA1, 1, 64);
    float cA2 = __shfl_up(vA2, 1, 64);
    float cB1 = __shfl_up(vB1, 1, 64);
    float cB2 = __shfl_up(vB2, 1, 64);
    if (lane == 0) { cA1 = 0.f; cA2 = 0.f; cB1 = 0.f; cB2 = 0.f; }

    // ---- cross-wave totals via LDS (8 A-totals + 8 B-totals), one barrier ----
    __shared__ float tA1[NWAVE], tA2[NWAVE], tB1[NWAVE], tB2[NWAVE];
    if (lane == 63) { tA1[wid] = vA1; tA2[wid] = vA2; tB1[wid] = vB1; tB2[wid] = vB2; }
    __syncthreads();

    const float Dw = d[6];                        // alpha^1024 (per-wave span)
    // carry base for A chunk: combine TA_0..TA_{wid-1}
    float WA1 = 0.f, WA2 = 0.f;
    for (int v = 0; v < wid; ++v) {
        WA1 = fmaf(WA1, Dw, tA1[v]);
        WA2 = fmaf(WA2, Dw, tA2[v]);
    }
    // carry base for B chunk: all of A, then TB_0..TB_{wid-1}
    float WB1 = WA1, WB2 = WA2;
    for (int v = wid; v < NWAVE; ++v) {
        WB1 = fmaf(WB1, Dw, tA1[v]);
        WB2 = fmaf(WB2, Dw, tA2[v]);
    }
    for (int v = 0; v < wid; ++v) {
        WB1 = fmaf(WB1, Dw, tB1[v]);
        WB2 = fmaf(WB2, Dw, tB2[v]);
    }
    // decay wave carry to this lane's chunk start: alpha^(16*lane)
    float fdec = 1.f;
#pragma unroll
    for (int k = 0; k < 6; ++k) if (lane & (1 << k)) fdec *= d[k];
    cA1 = fmaf(WA1, fdec, cA1);
    cA2 = fmaf(WA2, fdec, cA2);
    cB1 = fmaf(WB1, fdec, cB1);
    cB2 = fmaf(WB2, fdec, cB2);

    // ---- starting bias weights: w0 = K*(1 - alpha^t0); tid 0 exact ref path ----
    float pwA = 1.f;
#pragma unroll
    for (int k = 0; k < 9; ++k) if (tid & (1 << k)) pwA *= d[k];   // alpha^(16*tid)
    float w0A = (tid == 0) ? 0.f : Kf * (1.f - pwA);
    float pwB = pwA * d[9];                                        // alpha^(8192+16*tid)
    float w0B = Kf * (1.f - pwB);

    // ---- pass 2: recompute with carries, fused normalize, store ----
    float4 ovA[4], ovB[4];
    process16(xvA, ovA, cA1, cA2, w0A);
    process16(xvB, ovB, cB1, cB2, w0B);
#pragma unroll
    for (int i = 0; i < 4; ++i) yrA[i] = ovA[i];
#pragma unroll
    for (int i = 0; i < 4; ++i) yrB[i] = ovB[i];
}

extern "C" void kernel_launch(void* const* d_in, const int* in_sizes, int n_in,
                              void* d_out, int out_size, void* d_ws, size_t ws_size,
                              hipStream_t stream) {
    const float* x = (const float*)d_in[0];
    float* y = (float*)d_out;
    const int rows = in_sizes[0] / T_LEN;   // B*C = 2048
    ema_norm_kernel<<<rows, NTHR, 0, stream>>>(x, y);
}

// Round 5
// 233.407 us; speedup vs baseline: 1.2899x; 1.2899x over previous
//
#include <hip/hip_runtime.h>

#define T_LEN  16384
#define NTHR   384             // 6 waves; block covers 6144 elems (2048 halo + 4096 seg)
#define NWAVE  6
#define SEGS   4               // segments per row, 4096 elems each
#define TOT4   1536            // float4s per block window (6144 floats)
#define PAD4(i) ((i) + ((i) >> 4))   // +1 float4 pad per 16 -> conflict-free-ish

// Causal unbiased-EMA instance norm. Grid = 2048 rows x 4 segments, fully
// independent blocks: each block covers [seg*4096 - 2048, seg*4096 + 4096);
// the 2048-elem halo warms the EMA state (alpha^2048 ~ 1e-9 truncation, far
// below threshold). Seg 0's halo is hard zeros -> exact reference path at t=0.
// All global I/O is lane-contiguous float4 (1KB/wave-instruction = full 128B
// lines; R4 showed 64B-stride stores cause 3.4x RMW write amplification).
// LDS (padded) transposes between I/O layout and per-thread 16-elem chunks.

__device__ __forceinline__ void process16(const float4* __restrict__ xv,
                                          float4* __restrict__ yv,
                                          float s1, float s2, float w) {
    const float A    = 0.99f;
    const float OMA  = (float)(1.0 - 0.99);
    const float EPSF = 1e-5f;
#pragma unroll
    for (int i = 0; i < 4; ++i) {
        float4 xq = xv[i];
        float4 oq;
#pragma unroll
        for (int e = 0; e < 4; ++e) {
            float xi = (e == 0) ? xq.x : (e == 1) ? xq.y : (e == 2) ? xq.z : xq.w;
            float t = OMA * xi;
            s1 = fmaf(A, s1, t);
            s2 = fmaf(A, s2, t * xi);
            w  = fmaf(A, w, OMA);
            float numer = fmaf(xi, w, -s1);
            float arg   = fmaf(s2, w, fmaf(-s1, s1, EPSF * (w * w)));
            float rs    = __builtin_amdgcn_rsqf(arg);
            float o     = numer * rs;
            if (e == 0) oq.x = o; else if (e == 1) oq.y = o; else if (e == 2) oq.z = o; else oq.w = o;
        }
        yv[i] = oq;
    }
}

__global__ __launch_bounds__(NTHR, 8)
void ema_norm_kernel(const float* __restrict__ x, float* __restrict__ y) {
    const float A   = 0.99f;
    const float OMA = (float)(1.0 - 0.99);
    const float Kf  = (float)((double)((float)(1.0 - 0.99)) / (1.0 - (double)0.99f));

    // XCD-bijective swizzle: 8192 blocks = 8 x 1024; keep a row's segments on
    // one XCD so halo re-reads hit that XCD's L2.
    const int o   = (blockIdx.x & 7) * 1024 + (blockIdx.x >> 3);
    const int row = o >> 2;
    const int seg = o & 3;

    const int tid  = threadIdx.x;
    const int lane = tid & 63;
    const int wid  = tid >> 6;

    const float4* __restrict__ xr4 = reinterpret_cast<const float4*>(x + (size_t)row * T_LEN);
    float4*       __restrict__ yr4 = reinterpret_cast<float4*>(y + (size_t)row * T_LEN);

    __shared__ float4 buf[TOT4 + TOT4 / 16];     // 1632 float4s, padded
    __shared__ float  tW1[NWAVE], tW2[NWAVE];

    const int base4 = seg * 1024 - 512;          // window start, float4 units

    // ---- phase 0: coalesced full-line load -> LDS (transpose stage) ----
#pragma unroll
    for (int k = 0; k < 4; ++k) {
        int i = tid + NTHR * k;                  // [0, 1536)
        int g = base4 + i;
        float4 v = make_float4(0.f, 0.f, 0.f, 0.f);
        if (g >= 0) v = xr4[g];                  // seg 0 halo: hard zeros
        buf[PAD4(i)] = v;
    }
    __syncthreads();

    // ---- phase 1: own 16 contiguous elems from LDS, local EMA scan ----
    float4 xv[4];
#pragma unroll
    for (int c = 0; c < 4; ++c) { int i = 4 * tid + c; xv[c] = buf[PAD4(i)]; }

    float s1 = 0.f, s2 = 0.f;
#pragma unroll
    for (int i = 0; i < 4; ++i) {
        float t;
        t = OMA * xv[i].x; s1 = fmaf(A, s1, t); s2 = fmaf(A, s2, t * xv[i].x);
        t = OMA * xv[i].y; s1 = fmaf(A, s1, t); s2 = fmaf(A, s2, t * xv[i].y);
        t = OMA * xv[i].z; s1 = fmaf(A, s1, t); s2 = fmaf(A, s2, t * xv[i].z);
        t = OMA * xv[i].w; s1 = fmaf(A, s1, t); s2 = fmaf(A, s2, t * xv[i].w);
    }

    // decay constants d[k] = alpha^(16 * 2^k), exact repeated squaring
    float a16 = A;
#pragma unroll
    for (int i = 0; i < 4; ++i) a16 *= a16;      // alpha^16
    float d[10];
    d[0] = a16;
#pragma unroll
    for (int k = 1; k < 10; ++k) d[k] = d[k - 1] * d[k - 1];

    // ---- wave-level inclusive scan (Hillis-Steele with decay) ----
    float v1 = s1, v2 = s2;
#pragma unroll
    for (int k = 0; k < 6; ++k) {
        const int off = 1 << k;
        float o1 = __shfl_up(v1, off, 64);
        float o2 = __shfl_up(v2, off, 64);
        if (lane >= off) { v1 = fmaf(d[k], o1, v1); v2 = fmaf(d[k], o2, v2); }
    }
    float c1 = __shfl_up(v1, 1, 64);
    float c2 = __shfl_up(v2, 1, 64);
    if (lane == 0) { c1 = 0.f; c2 = 0.f; }

    // ---- cross-wave scan (6 waves, decay alpha^1024) ----
    if (lane == 63) { tW1[wid] = v1; tW2[wid] = v2; }
    __syncthreads();
    float W1 = 0.f, W2 = 0.f;
    const float Dw = d[6];                       // alpha^1024
    for (int v = 0; v < wid; ++v) {
        W1 = fmaf(W1, Dw, tW1[v]);
        W2 = fmaf(W2, Dw, tW2[v]);
    }
    float fdec = 1.f;
#pragma unroll
    for (int k = 0; k < 6; ++k) if (lane & (1 << k)) fdec *= d[k];
    c1 = fmaf(W1, fdec, c1);
    c2 = fmaf(W2, fdec, c2);

    // ---- starting bias weight w0 = K*(1 - alpha^(16*m)), m = global chunk idx ----
    const int m = 256 * seg - 128 + tid;         // global t0 / 16
    float w0 = 0.f;
    if (m > 0) {
        float pw = 1.f;
#pragma unroll
        for (int k = 0; k < 10; ++k) if (m & (1 << k)) pw *= d[k];
        w0 = Kf * (1.f - pw);
    }                                            // m<=0: exact ref start (w=0)

    // ---- pass 2: recompute + fused normalize, results back into LDS ----
    float4 ov[4];
    process16(xv, ov, c1, c2, w0);
#pragma unroll
    for (int c = 0; c < 4; ++c) { int i = 4 * tid + c; buf[PAD4(i)] = ov[c]; }
    __syncthreads();

    // ---- phase 3: coalesced full-line store of active region [512,1536) ----
#pragma unroll
    for (int k = 0; k < 3; ++k) {
        int i = tid + NTHR * k;                  // [0, 1152)
        if (i < 1024) {
            int s = 512 + i;
            yr4[seg * 1024 + i] = buf[PAD4(s)];
        }
    }
}

extern "C" void kernel_launch(void* const* d_in, const int* in_sizes, int n_in,
                              void* d_out, int out_size, void* d_ws, size_t ws_size,
                              hipStream_t stream) {
    const float* x = (const float*)d_in[0];
    float* y = (float*)d_out;
    const int rows = in_sizes[0] / T_LEN;        // B*C = 2048
    ema_norm_kernel<<<rows * SEGS, NTHR, 0, stream>>>(x, y);
}